// Round 4
// baseline (2208.506 us; speedup 1.0000x reference)
//
#include <hip/hip_runtime.h>
#include <math.h>

#define KNB 26
#define DD 32
#define NH 32

// tanh(x) = 1 - 2/(1 + e^{2x}).  v_exp_f32 + v_rcp_f32 path (~5 instrs vs ~20+ for ocml tanhf).
// Saturates: x->+inf => 1-2/inf = 1; x->-inf => exp->0 => 1-2 = -1. abs err ~4e-7.
__device__ __forceinline__ float fast_tanh(float x) {
    return 1.0f - __fdividef(2.0f, 1.0f + __expf(2.0f * x));
}
__device__ __forceinline__ float fast_sigmoid(float x) {
    return __fdividef(1.0f, 1.0f + __expf(-x));
}

__device__ __forceinline__ void load32(float (&dst)[DD], const float4* __restrict__ p) {
    #pragma unroll
    for (int i = 0; i < DD / 4; ++i) {
        float4 v = p[i];
        dst[4*i+0] = v.x; dst[4*i+1] = v.y; dst[4*i+2] = v.z; dst[4*i+3] = v.w;
    }
}

// acc[d] += sum_k in[k] * W[k*DD + d]   (W wave-uniform -> s_load batches, K$-resident)
__device__ __forceinline__ void matvec32(const float* __restrict__ W,
                                         const float (&in)[DD], float (&acc)[DD]) {
    #pragma unroll 4
    for (int k = 0; k < DD; ++k) {
        const float v = in[k];
        #pragma unroll
        for (int d = 0; d < DD; ++d) acc[d] = fmaf(v, W[k*DD + d], acc[d]);
    }
}

// Branchless: every neighbor runs the message matmul (random tiers => every wave has
// tier-1 lanes with prob ~1-6e-12, so divergence would force it anyway); tier masks
// weight the accumulators. Uniform instruction stream, no exec-mask churn.
__device__ __forceinline__ void process_neighbor(
    const float (&nbv)[DD], int t,
    float (&s_all)[DD], float (&s_loc)[DD], float (&s_dis)[DD], float (&s_msg)[DD],
    float& cnt_loc, float& cnt_fun, float& cnt_dis,
    const float* __restrict__ Wm, const float* __restrict__ bm)
{
    const float m0 = (t == 0) ? 1.0f : 0.0f;
    const float m1 = (t == 1) ? 1.0f : 0.0f;
    const float m2 = (t == 2) ? 1.0f : 0.0f;
    cnt_loc += m0; cnt_fun += m1; cnt_dis += m2;

    float acc[DD];
    #pragma unroll
    for (int d = 0; d < DD; ++d) acc[d] = bm[d];   // wave-uniform, K$-hit reloads
    #pragma unroll
    for (int k = 0; k < DD; ++k) {
        const float v = nbv[k];
        #pragma unroll
        for (int d = 0; d < DD; ++d) acc[d] = fmaf(v, Wm[k*DD + d], acc[d]);
    }
    #pragma unroll
    for (int d = 0; d < DD; ++d) {
        s_all[d] += nbv[d];
        s_loc[d] = fmaf(m0, nbv[d], s_loc[d]);
        s_dis[d] = fmaf(m2, nbv[d], s_dis[d]);
        s_msg[d] = fmaf(m1, fast_tanh(acc[d]), s_msg[d]);
    }
}

__global__ __launch_bounds__(256, 2) void moe_fused(
    const float* __restrict__ cur_g, const float* __restrict__ nb_g,
    const int* __restrict__ tier_g,
    const float* __restrict__ Wl,  const float* __restrict__ blv,
    const float* __restrict__ Wm,  const float* __restrict__ bm,
    const float* __restrict__ Wu,  const float* __restrict__ bu,
    const float* __restrict__ Wc,  const float* __restrict__ bc,
    const float* __restrict__ Wg1, const float* __restrict__ bg1,
    const float* __restrict__ Wg2, const float* __restrict__ bg2,
    float* __restrict__ out_g, int ncells)
{
    const int cell = blockIdx.x * 256 + threadIdx.x;
    if (cell >= ncells) return;

    float s_all[DD], s_loc[DD], s_dis[DD], s_msg[DD];
    #pragma unroll
    for (int d = 0; d < DD; ++d) { s_all[d] = 0.f; s_loc[d] = 0.f; s_dis[d] = 0.f; s_msg[d] = 0.f; }
    float cnt_loc = 0.f, cnt_fun = 0.f, cnt_dis = 0.f;

    const float4* np4 = reinterpret_cast<const float4*>(nb_g + (size_t)cell * (KNB * DD));
    // tier row base = cell*104 B (13x8 B) -> 8B-aligned; j steps by 2 -> int2 loads are aligned.
    const int2* tp2 = reinterpret_cast<const int2*>(tier_g + (size_t)cell * KNB);

    // ping-pong prefetch (static buffers only — runtime-indexed arrays spill to scratch)
    float bufA[DD], bufB[DD];
    load32(bufA, np4);
    #pragma unroll 1
    for (int j = 0; j < KNB; j += 2) {
        const int2 tAB = tp2[j >> 1];             // tiers for neighbors j, j+1
        load32(bufB, np4 + (size_t)(j + 1) * (DD / 4));
        process_neighbor(bufA, tAB.x, s_all, s_loc, s_dis, s_msg, cnt_loc, cnt_fun, cnt_dis, Wm, bm);
        if (j + 2 < KNB) load32(bufA, np4 + (size_t)(j + 2) * (DD / 4));
        process_neighbor(bufB, tAB.y, s_all, s_loc, s_dis, s_msg, cnt_loc, cnt_fun, cnt_dis, Wm, bm);
    }

    // current state loaded once, after the hot loop (keeps loop-phase VGPRs down)
    float cur[DD];
    load32(cur, reinterpret_cast<const float4*>(cur_g + (size_t)cell * DD));

    const float inv_all = 1.0f / (float)KNB;
    const float inv_loc = __fdividef(1.0f, fmaxf(cnt_loc, 1.0f));
    const float inv_fun = __fdividef(1.0f, fmaxf(cnt_fun, 1.0f));
    const float inv_dis = __fdividef(1.0f, fmaxf(cnt_dis, 1.0f));
    #pragma unroll
    for (int d = 0; d < DD; ++d) {
        s_all[d] *= inv_all;  // mean_nb
        s_loc[d] *= inv_loc;  // loc_mean
        s_msg[d] *= inv_fun;  // agg (masked mean of tanh msgs)
        s_dis[d] *= inv_dis;  // agg_d
    }

    // ---- gating ----
    float h[NH];
    #pragma unroll
    for (int d = 0; d < NH; ++d) h[d] = bg1[d];
    matvec32(Wg1, cur, h);
    matvec32(Wg1 + DD * NH, s_all, h);
    float l0 = bg2[0], l1 = bg2[1], l2 = bg2[2];
    #pragma unroll
    for (int j = 0; j < NH; ++j) {
        const float hj = fmaxf(h[j], 0.0f);
        l0 = fmaf(hj, Wg2[j*3 + 0], l0);
        l1 = fmaf(hj, Wg2[j*3 + 1], l1);
        l2 = fmaf(hj, Wg2[j*3 + 2], l2);
    }
    const float mx = fmaxf(l0, fmaxf(l1, l2));
    const float e0 = __expf(l0 - mx), e1 = __expf(l1 - mx), e2 = __expf(l2 - mx);
    const float inv_e = __fdividef(1.0f, e0 + e1 + e2);
    const float g0 = e0 * inv_e, g1 = e1 * inv_e, g2 = e2 * inv_e;

    float outv[DD];

    // ---- local expert ----
    {
        float a[DD];
        #pragma unroll
        for (int d = 0; d < DD; ++d) a[d] = blv[d];
        matvec32(Wl, cur, a);
        matvec32(Wl + DD * DD, s_loc, a);
        #pragma unroll
        for (int d = 0; d < DD; ++d) outv[d] = g0 * fast_tanh(a[d]);
    }

    // ---- functional expert ----
    {
        float a[DD];
        #pragma unroll
        for (int d = 0; d < DD; ++d) a[d] = bu[d];
        matvec32(Wu, cur, a);
        matvec32(Wu + DD * DD, s_msg, a);
        #pragma unroll
        for (int d = 0; d < DD; ++d) {
            const float z = fast_sigmoid(a[d]);
            const float f = (1.0f - z) * cur[d] + z * fast_tanh(s_msg[d]);
            outv[d] = fmaf(g1, f, outv[d]);
        }
    }

    // ---- distant expert (3-step Euler CNF) ----
    {
        float c2[DD];  // loop-invariant half: agg_d @ W_cnf[D:] + b_cnf
        #pragma unroll
        for (int d = 0; d < DD; ++d) c2[d] = bc[d];
        matvec32(Wc + DD * DD, s_dis, c2);
        const float dt = 1.0f / 3.0f;
        float x[DD];
        #pragma unroll
        for (int d = 0; d < DD; ++d) x[d] = cur[d];
        #pragma unroll 1
        for (int s = 0; s < 3; ++s) {
            float a[DD];
            #pragma unroll
            for (int d = 0; d < DD; ++d) a[d] = c2[d];
            matvec32(Wc, x, a);
            #pragma unroll
            for (int d = 0; d < DD; ++d) x[d] = fmaf(dt, fast_tanh(a[d]), x[d]);
        }
        #pragma unroll
        for (int d = 0; d < DD; ++d) outv[d] = fmaf(g2, x[d], outv[d]);
    }

    float4* op = reinterpret_cast<float4*>(out_g + (size_t)cell * DD);
    #pragma unroll
    for (int i = 0; i < DD / 4; ++i)
        op[i] = make_float4(outv[4*i], outv[4*i+1], outv[4*i+2], outv[4*i+3]);
}

extern "C" void kernel_launch(void* const* d_in, const int* in_sizes, int n_in,
                              void* d_out, int out_size, void* d_ws, size_t ws_size,
                              hipStream_t stream) {
    const float* cur = (const float*)d_in[0];
    const float* nb  = (const float*)d_in[1];
    const int*   tid = (const int*)d_in[2];
    const float* Wl  = (const float*)d_in[3];
    const float* bl  = (const float*)d_in[4];
    const float* Wm  = (const float*)d_in[5];
    const float* bm  = (const float*)d_in[6];
    const float* Wu  = (const float*)d_in[7];
    const float* bu  = (const float*)d_in[8];
    const float* Wc  = (const float*)d_in[9];
    const float* bc  = (const float*)d_in[10];
    const float* Wg1 = (const float*)d_in[11];
    const float* bg1 = (const float*)d_in[12];
    const float* Wg2 = (const float*)d_in[13];
    const float* bg2 = (const float*)d_in[14];
    float* out = (float*)d_out;

    const int ncells = in_sizes[0] / DD;           // 262144
    const int grid = (ncells + 255) / 256;         // 1024 blocks
    moe_fused<<<grid, 256, 0, stream>>>(cur, nb, tid, Wl, bl, Wm, bm, Wu, bu,
                                        Wc, bc, Wg1, bg1, Wg2, bg2, out, ncells);
}